// Round 15
// baseline (432.689 us; speedup 1.0000x reference)
//
#include <hip/hip_runtime.h>
#include <hip/hip_cooperative_groups.h>

namespace cg = cooperative_groups;

#define B_ 4
#define C_ 256
#define D_ 128
#define N_ 4096
#define BN_ 16384   // B_*N_

typedef unsigned short u16t;
typedef _Float16 f16t;
typedef f16t f16x8 __attribute__((ext_vector_type(8)));
typedef f16t f16x4 __attribute__((ext_vector_type(4)));
typedef float f32x4 __attribute__((ext_vector_type(4)));

static __device__ __forceinline__ u16t f2h(float f) {
  f16t h = (f16t)f; u16t u; __builtin_memcpy(&u, &h, 2); return u;
}
static __device__ __forceinline__ float h2f(u16t u) {
  f16t h; __builtin_memcpy(&h, &u, 2); return (float)h;
}

// async 16B global->LDS DMA (zero VGPR staging). LDS dest is wave-uniform base + lane*16.
static __device__ __forceinline__ void gld_lds16(const u16t* g, u16t* l) {
  __builtin_amdgcn_global_load_lds(
      (const __attribute__((address_space(1))) void*)g,
      (__attribute__((address_space(3))) void*)l, 16, 0, 0);
}

// ==================== v14 mega kernel (cooperative, 5 phases) ====================
__global__ __launch_bounds__(256, 2) void mega(
    const float* __restrict__ x,
    const float* __restrict__ th_w, const float* __restrict__ ph_w,
    const float* __restrict__ th_b, const float* __restrict__ ph_b,
    const float* __restrict__ g_w, const float* __restrict__ g_b,
    const float* __restrict__ w_w, const float* __restrict__ w_b,
    const float* __restrict__ gamma, const float* __restrict__ beta,
    float* out,
    u16t* xT,      // ws+0: xT (phases 0-1), then O0 = attn splits 0,1 (phases 2-3)
    u16t* QK,      // ws+8M: QK (phases 1-2), then wy (phases 3-4)
    u16t* __restrict__ V,
    u16t* __restrict__ Wc, u16t* __restrict__ gwc, u16t* __restrict__ wwc,
    float* __restrict__ bc, float* __restrict__ ml,
    u16t* O2) {    // d_out: attn splits 2,3 (phases 2-3), overwritten by out (phase 4)
  __shared__ __attribute__((aligned(16))) char smem[65536];
  cg::grid_group gg = cg::this_grid();
  const int fblk = blockIdx.x;
  const int tid = threadIdx.x, lane = tid & 63, wave = tid >> 6;
  const int quad = lane >> 4, l16 = lane & 15;
  const int wm = wave & 1, wj = wave >> 1;
  const f32x4 zero = {0.f, 0.f, 0.f, 0.f};

  // ===== phase 0: weight prep + transpose =====
  if (fblk < 128) {
    for (int idx = fblk * 256 + tid; idx < 131328; idx += 32768) {
      if (idx < 65536) {
        const int j = idx >> 8, c = idx & 255;
        const float v = (j < 128) ? th_w[j * 256 + c] : ph_w[(j - 128) * 256 + c];
        Wc[idx] = f2h(v);
      } else if (idx < 98304) {
        gwc[idx - 65536] = f2h(g_w[idx - 65536]);
      } else if (idx < 131072) {
        wwc[idx - 98304] = f2h(w_w[idx - 98304]);
      } else {
        const int j = idx - 131072;
        bc[j] = (j < 128) ? th_b[j] : ph_b[j - 128];
      }
    }
  }
  {
    u16t (*t)[33] = (u16t (*)[33])smem;
    for (int i = 0; i < 8; ++i) {
      const int tt = i * 512 + fblk;
      const int bx = tt & 127, by = (tt >> 7) & 7, bz = tt >> 10;
      const int c0 = by * 32, n0 = bx * 32;
      {
        const int cl = tid >> 3, n4 = (tid & 7) * 4;
        const float4 v = *(const float4*)(x + ((size_t)bz * C_ + c0 + cl) * N_ + n0 + n4);
        t[n4 + 0][cl] = f2h(v.x);
        t[n4 + 1][cl] = f2h(v.y);
        t[n4 + 2][cl] = f2h(v.z);
        t[n4 + 3][cl] = f2h(v.w);
      }
      __syncthreads();
      {
        const int nl = tid >> 3, c4 = (tid & 7) * 4;
        unsigned lo = (unsigned)t[nl][c4 + 0] | ((unsigned)t[nl][c4 + 1] << 16);
        unsigned hi = (unsigned)t[nl][c4 + 2] | ((unsigned)t[nl][c4 + 3] << 16);
        uint2 o; o.x = lo; o.y = hi;
        *(uint2*)(xT + ((size_t)bz * N_ + n0 + nl) * C_ + c0 + c4) = o;
      }
      __syncthreads();
    }
  }
  gg.sync();

  // ===== phase 1: QK + V projection (blocks 0..383) =====
  if (fblk < 384) {
    u16t* lA = (u16t*)smem;
    u16t* lB = (u16t*)(smem + 10240);
    const int z = fblk / 96, bx = fblk % 96;
    const u16t* xTb = xT + (size_t)z * N_ * C_;
    const u16t* A; const u16t* B; u16t* Cb; int ldc, m0, j0, colb;
    const float* bias;
    if (bx < 64) {
      A = xTb; B = Wc; Cb = QK + (size_t)z * N_ * 256; ldc = 256;
      m0 = (bx >> 1) * 128; j0 = (bx & 1) * 128; bias = bc; colb = 1;
    } else {
      A = gwc; B = xTb; Cb = V + (size_t)z * D_ * N_; ldc = N_;
      m0 = 0; j0 = (bx - 64) * 128; bias = g_b; colb = 0;
    }
    f32x4 acc[4][4];
#pragma unroll
    for (int mi = 0; mi < 4; ++mi)
#pragma unroll
      for (int ji = 0; ji < 4; ++ji) acc[mi][ji] = zero;

    for (int k0 = 0; k0 < 256; k0 += 32) {
#pragma unroll
      for (int rr = 0; rr < 2; ++rr) {
        const int idx = rr * 256 + tid;
        const int row = idx >> 2, sg = idx & 3;
        *(uint4*)&lA[row * 40 + sg * 8] = *(const uint4*)(A + (size_t)(m0 + row) * 256 + k0 + sg * 8);
        *(uint4*)&lB[row * 40 + sg * 8] = *(const uint4*)(B + (size_t)(j0 + row) * 256 + k0 + sg * 8);
      }
      __syncthreads();
      f16x8 af[4], bfr[4];
#pragma unroll
      for (int i = 0; i < 4; ++i)
        af[i] = *(const f16x8*)&lA[(wm * 64 + i * 16 + l16) * 40 + quad * 8];
#pragma unroll
      for (int i = 0; i < 4; ++i)
        bfr[i] = *(const f16x8*)&lB[(wj * 64 + i * 16 + l16) * 40 + quad * 8];
#pragma unroll
      for (int mi = 0; mi < 4; ++mi)
#pragma unroll
        for (int ji = 0; ji < 4; ++ji)
          acc[mi][ji] = __builtin_amdgcn_mfma_f32_16x16x32_f16(af[mi], bfr[ji], acc[mi][ji], 0, 0, 0);
      __syncthreads();
    }

    float cb[4];
    if (colb) {
#pragma unroll
      for (int ji = 0; ji < 4; ++ji) cb[ji] = bias[j0 + wj * 64 + ji * 16 + l16];
    }
#pragma unroll
    for (int mi = 0; mi < 4; ++mi) {
#pragma unroll
      for (int r = 0; r < 4; ++r) {
        const int row = m0 + wm * 64 + mi * 16 + quad * 4 + r;
        const float rb = colb ? 0.f : bias[row];
#pragma unroll
        for (int ji = 0; ji < 4; ++ji) {
          const int col = j0 + wj * 64 + ji * 16 + l16;
          const float v = acc[mi][ji][r] + (colb ? cb[ji] : rb);
          Cb[(size_t)row * ldc + col] = f2h(v);
        }
      }
    }
  }
  gg.sync();

  // ===== phase 2: flash attention (all 512 blocks) =====
  {
    u16t* Ksm = (u16t*)smem;
    u16t* Vsm = (u16t*)(smem + 32768);
    const int n0 = (fblk & 31) * 128;
    const int ab = (fblk >> 5) & 3;
    const int split = fblk >> 7;
    const int kv0 = split * (N_ / 4);
    const int x7 = l16 & 7;
    const u16t* QKb = QK + (size_t)ab * N_ * 256;
    const u16t* Vb  = V  + (size_t)ab * D_ * N_;
    const int krow_l = lane >> 4, kchunk_l = lane & 15;
    const int vrow_l = lane >> 3, vchunk_l = lane & 7;

    f16x8 qf[2][4];
#pragma unroll
    for (int qi = 0; qi < 2; ++qi) {
      const u16t* qrow = QKb + (size_t)(n0 + wave * 32 + qi * 16 + l16) * 256;
#pragma unroll
      for (int kc = 0; kc < 4; ++kc)
        qf[qi][kc] = *(const f16x8*)(qrow + kc * 32 + quad * 8);
    }

    f32x4 o[2][8];
#pragma unroll
    for (int qi = 0; qi < 2; ++qi)
#pragma unroll
      for (int db = 0; db < 8; ++db) o[qi][db] = zero;
    float m[2] = {-1e30f, -1e30f}, l[2] = {0.f, 0.f};

#pragma unroll
    for (int i = 0; i < 4; ++i) {
      const int krow = (wave * 4 + i) * 4 + krow_l;
      const int kcl = kchunk_l ^ (krow & 7);
      gld_lds16(QKb + (size_t)(kv0 + krow) * 256 + 128 + kcl * 8,
                Ksm + (wave * 4 + i) * 512);
    }
#pragma unroll
    for (int i = 0; i < 4; ++i) {
      const int vrow = (wave * 4 + i) * 8 + vrow_l;
      const int vcl = vchunk_l ^ (vrow & 7);
      gld_lds16(Vb + (size_t)vrow * N_ + kv0 + vcl * 8,
                Vsm + (wave * 4 + i) * 512);
    }
    __syncthreads();

    int cur = 0;
    for (int it = 0; it < 16; ++it) {
      if (it < 15) {
        const int kvn = kv0 + (it + 1) * 64;
#pragma unroll
        for (int i = 0; i < 4; ++i) {
          const int krow = (wave * 4 + i) * 4 + krow_l;
          const int kcl = kchunk_l ^ (krow & 7);
          gld_lds16(QKb + (size_t)(kvn + krow) * 256 + 128 + kcl * 8,
                    Ksm + (cur ^ 1) * 8192 + (wave * 4 + i) * 512);
        }
#pragma unroll
        for (int i = 0; i < 4; ++i) {
          const int vrow = (wave * 4 + i) * 8 + vrow_l;
          const int vcl = vchunk_l ^ (vrow & 7);
          gld_lds16(Vb + (size_t)vrow * N_ + kvn + vcl * 8,
                    Vsm + (cur ^ 1) * 8192 + (wave * 4 + i) * 512);
        }
      }

      const u16t* KsC = Ksm + cur * 8192;
      const u16t* VsC = Vsm + cur * 8192;

      f32x4 s[2][4];
#pragma unroll
      for (int qi = 0; qi < 2; ++qi)
#pragma unroll
        for (int ci = 0; ci < 4; ++ci) s[qi][ci] = zero;
#pragma unroll
      for (int kc = 0; kc < 4; ++kc) {
#pragma unroll
        for (int ci = 0; ci < 4; ++ci) {
          f16x8 kf = *(const f16x8*)&KsC[(ci * 16 + l16) * 128 + (((kc * 4 + quad) ^ x7) << 3)];
          s[0][ci] = __builtin_amdgcn_mfma_f32_16x16x32_f16(kf, qf[0][kc], s[0][ci], 0, 0, 0);
          s[1][ci] = __builtin_amdgcn_mfma_f32_16x16x32_f16(kf, qf[1][kc], s[1][ci], 0, 0, 0);
        }
      }

      f16x4 pb[2][4];
#pragma unroll
      for (int qi = 0; qi < 2; ++qi) {
        float m0_ = fmaxf(fmaxf(s[qi][0][0], s[qi][0][1]), fmaxf(s[qi][0][2], s[qi][0][3]));
        float m1_ = fmaxf(fmaxf(s[qi][1][0], s[qi][1][1]), fmaxf(s[qi][1][2], s[qi][1][3]));
        float m2_ = fmaxf(fmaxf(s[qi][2][0], s[qi][2][1]), fmaxf(s[qi][2][2], s[qi][2][3]));
        float m3_ = fmaxf(fmaxf(s[qi][3][0], s[qi][3][1]), fmaxf(s[qi][3][2], s[qi][3][3]));
        float mx = fmaxf(fmaxf(m0_, m1_), fmaxf(m2_, m3_));
        mx = fmaxf(mx, __shfl_xor(mx, 16));
        mx = fmaxf(mx, __shfl_xor(mx, 32));
        const bool defer = __all(mx <= m[qi] + 8.f);
        float mnew = m[qi];
        if (!defer) {
          mnew = fmaxf(m[qi], mx);
          const float alq = __expf(m[qi] - mnew);
          l[qi] *= alq;
#pragma unroll
          for (int db = 0; db < 8; ++db) {
#pragma unroll
            for (int r = 0; r < 4; ++r) o[qi][db][r] *= alq;
          }
          m[qi] = mnew;
        }
        float psum = 0.f;
#pragma unroll
        for (int ci = 0; ci < 4; ++ci) {
#pragma unroll
          for (int r = 0; r < 4; ++r) {
            const float p = __expf(s[qi][ci][r] - mnew);
            psum += p;
            pb[qi][ci][r] = (f16t)p;
          }
        }
        psum += __shfl_xor(psum, 16);
        psum += __shfl_xor(psum, 32);
        l[qi] += psum;
      }

#pragma unroll
      for (int ci = 0; ci < 4; ++ci) {
#pragma unroll
        for (int db = 0; db < 8; ++db) {
          f16x4 av = *(const f16x4*)&VsC[(db * 16 + l16) * 64 +
                                         (((ci * 2 + (quad >> 1)) ^ x7) << 3) + (quad & 1) * 4];
          o[0][db] = __builtin_amdgcn_mfma_f32_16x16x16f16(av, pb[0][ci], o[0][db], 0, 0, 0);
          o[1][db] = __builtin_amdgcn_mfma_f32_16x16x16f16(av, pb[1][ci], o[1][db], 0, 0, 0);
        }
      }
      __syncthreads();
      cur ^= 1;
    }

    u16t* Onb = (split < 2) ? xT : O2;
    const int sp = split & 1;
#pragma unroll
    for (int qi = 0; qi < 2; ++qi) {
      const int q = n0 + wave * 32 + qi * 16 + l16;
      const float inv = 1.0f / l[qi];
      u16t* yrow = Onb + (((size_t)sp * B_ + ab) * N_ + q) * D_;
#pragma unroll
      for (int db = 0; db < 8; ++db) {
        f16x4 pk;
#pragma unroll
        for (int r = 0; r < 4; ++r) pk[r] = (f16t)(o[qi][db][r] * inv);
        *(f16x4*)(yrow + db * 16 + quad * 4) = pk;
      }
      if (quad == 0) {
        float* mlp = ml + ((size_t)split * BN_ + (size_t)ab * N_ + q) * 2;
        mlp[0] = m[qi]; mlp[1] = l[qi];
      }
    }
  }
  gg.sync();

  // ===== phase 3: w_y GEMM (all 512 blocks) =====
  {
    u16t* lA = (u16t*)smem;
    u16t* lB = (u16t*)(smem + 40960);
    float* wrow = (float*)(smem + 61440);
    const u16t* O0 = xT;
    u16t* wy = QK;
    const int z = fblk >> 7;
    const int m0 = ((fblk >> 6) & 1) * 128, j0 = (fblk & 63) * 64;
    const size_t halfO = (size_t)BN_ * D_;

    uint4 b0[4], b1[4], b2[4], b3[4];
#pragma unroll
    for (int cs = 0; cs < 4; ++cs) {
      const int cid = cs * 256 + tid;
      const int row = cid >> 4, sg = cid & 15;
      const size_t base = ((size_t)z * N_ + j0 + row) * D_ + sg * 8;
      b0[cs] = *(const uint4*)(O0 + base);
      b1[cs] = *(const uint4*)(O0 + halfO + base);
      b2[cs] = *(const uint4*)(O2 + base);
      b3[cs] = *(const uint4*)(O2 + halfO + base);
    }
    uint4 aw[8];
#pragma unroll
    for (int as = 0; as < 8; ++as) {
      const int cid = as * 256 + tid;
      const int row = cid >> 4, sg = cid & 15;
      aw[as] = *(const uint4*)(wwc + (size_t)(m0 + row) * 128 + sg * 8);
    }
    float mlv[8];
    if (tid < 64) {
      const int q = j0 + tid;
#pragma unroll
      for (int s = 0; s < 4; ++s) {
        mlv[2 * s]     = ml[((size_t)s * BN_ + (size_t)z * N_ + q) * 2];
        mlv[2 * s + 1] = ml[((size_t)s * BN_ + (size_t)z * N_ + q) * 2 + 1];
      }
      float mstar = -1e30f;
#pragma unroll
      for (int s = 0; s < 4; ++s) mstar = fmaxf(mstar, mlv[2 * s]);
      float w[4], wsum = 0.f;
#pragma unroll
      for (int s = 0; s < 4; ++s) { w[s] = __expf(mlv[2 * s] - mstar) * mlv[2 * s + 1]; wsum += w[s]; }
      const float inv = 1.0f / wsum;
#pragma unroll
      for (int s = 0; s < 4; ++s) wrow[tid * 4 + s] = w[s] * inv;
    }
#pragma unroll
    for (int as = 0; as < 8; ++as) {
      const int cid = as * 256 + tid;
      const int row = cid >> 4, sg = cid & 15;
      *(uint4*)&lA[(sg >> 2) * 5120 + row * 40 + (sg & 3) * 8] = aw[as];
    }
    __syncthreads();
#pragma unroll
    for (int cs = 0; cs < 4; ++cs) {
      const int cid = cs * 256 + tid;
      const int row = cid >> 4, sg = cid & 15;
      const float w0 = wrow[row * 4 + 0], w1 = wrow[row * 4 + 1];
      const float w2 = wrow[row * 4 + 2], w3 = wrow[row * 4 + 3];
      const unsigned* p0 = &b0[cs].x; const unsigned* p1 = &b1[cs].x;
      const unsigned* p2 = &b2[cs].x; const unsigned* p3 = &b3[cs].x;
      uint4 y; unsigned* py = &y.x;
#pragma unroll
      for (int i = 0; i < 4; ++i) {
        const float lo = w0 * h2f((u16t)(p0[i] & 0xffff)) + w1 * h2f((u16t)(p1[i] & 0xffff)) +
                         w2 * h2f((u16t)(p2[i] & 0xffff)) + w3 * h2f((u16t)(p3[i] & 0xffff));
        const float hi = w0 * h2f((u16t)(p0[i] >> 16)) + w1 * h2f((u16t)(p1[i] >> 16)) +
                         w2 * h2f((u16t)(p2[i] >> 16)) + w3 * h2f((u16t)(p3[i] >> 16));
        py[i] = (unsigned)f2h(lo) | ((unsigned)f2h(hi) << 16);
      }
      *(uint4*)&lB[(sg >> 2) * 2560 + row * 40 + (sg & 3) * 8] = y;
    }
    __syncthreads();

    f32x4 acc[4][2];
#pragma unroll
    for (int mi = 0; mi < 4; ++mi)
#pragma unroll
      for (int ji = 0; ji < 2; ++ji) acc[mi][ji] = zero;
#pragma unroll
    for (int kc = 0; kc < 4; ++kc) {
      f16x8 af[4], bfr[2];
#pragma unroll
      for (int i = 0; i < 4; ++i)
        af[i] = *(const f16x8*)&lA[kc * 5120 + (wm * 64 + i * 16 + l16) * 40 + quad * 8];
#pragma unroll
      for (int i = 0; i < 2; ++i)
        bfr[i] = *(const f16x8*)&lB[kc * 2560 + (wj * 32 + i * 16 + l16) * 40 + quad * 8];
#pragma unroll
      for (int mi = 0; mi < 4; ++mi)
#pragma unroll
        for (int ji = 0; ji < 2; ++ji)
          acc[mi][ji] = __builtin_amdgcn_mfma_f32_16x16x32_f16(af[mi], bfr[ji], acc[mi][ji], 0, 0, 0);
    }

#pragma unroll
    for (int mi = 0; mi < 4; ++mi) {
#pragma unroll
      for (int r = 0; r < 4; ++r) {
        const int row = m0 + wm * 64 + mi * 16 + quad * 4 + r;
        const float rb = w_b[row];
#pragma unroll
        for (int ji = 0; ji < 2; ++ji) {
          const int col = j0 + wj * 32 + ji * 16 + l16;
          const float v = acc[mi][ji][r] + rb;
          wy[(size_t)z * C_ * N_ + (size_t)row * N_ + col] = f2h(v);
        }
      }
    }
  }
  gg.sync();

  // ===== phase 4: BN stats + finalize (blocks 0..255) =====
  if (fblk < 256) {
    const u16t* wy = QK;
    float* red = (float*)smem;
    float* mvs = (float*)(smem + 32);
    const int c = fblk;
    float s1 = 0.f, s2 = 0.f;
#pragma unroll
    for (int it = 0; it < 8; ++it) {
      const int e = (it * 256 + tid) * 8;
      const int z = e >> 12, n = e & 4095;
      const uint4 v = *(const uint4*)(wy + (size_t)z * C_ * N_ + (size_t)c * N_ + n);
      const unsigned* p = &v.x;
#pragma unroll
      for (int i = 0; i < 4; ++i) {
        const float lo = h2f((u16t)(p[i] & 0xffff));
        const float hi = h2f((u16t)(p[i] >> 16));
        s1 += lo + hi;
        s2 += lo * lo + hi * hi;
      }
    }
    s1 += __shfl_xor(s1, 1);  s2 += __shfl_xor(s2, 1);
    s1 += __shfl_xor(s1, 2);  s2 += __shfl_xor(s2, 2);
    s1 += __shfl_xor(s1, 4);  s2 += __shfl_xor(s2, 4);
    s1 += __shfl_xor(s1, 8);  s2 += __shfl_xor(s2, 8);
    s1 += __shfl_xor(s1, 16); s2 += __shfl_xor(s2, 16);
    s1 += __shfl_xor(s1, 32); s2 += __shfl_xor(s2, 32);
    if (lane == 0) { red[wave] = s1; red[4 + wave] = s2; }
    __syncthreads();
    if (tid == 0) {
      const float inv_n = 1.0f / 16384.0f;
      const float tot1 = red[0] + red[1] + red[2] + red[3];
      const float tot2 = red[4] + red[5] + red[6] + red[7];
      const float mean = tot1 * inv_n;
      const float var = tot2 * inv_n - mean * mean;
      mvs[0] = mean;
      mvs[1] = rsqrtf(var + 1e-5f);
    }
    __syncthreads();
    const float mean = mvs[0], rs = mvs[1];
    const float g = gamma[c], bt = beta[c];
#pragma unroll
    for (int it = 0; it < 16; ++it) {
      const int e4 = it * 256 + tid;
      const int z = e4 >> 10, n4 = (e4 & 1023) * 4;
      const size_t off = ((size_t)z * C_ + c) * N_ + n4;
      const uint2 wv = *(const uint2*)(wy + off);
      const float4 xv = *(const float4*)(x + off);
      float4 ov;
      ov.x = (h2f((u16t)(wv.x & 0xffff)) - mean) * rs * g + bt + xv.x;
      ov.y = (h2f((u16t)(wv.x >> 16))    - mean) * rs * g + bt + xv.y;
      ov.z = (h2f((u16t)(wv.y & 0xffff)) - mean) * rs * g + bt + xv.z;
      ov.w = (h2f((u16t)(wv.y >> 16))    - mean) * rs * g + bt + xv.w;
      *(float4*)(out + off) = ov;
    }
  }
}

// ==================== v13 fallback kernels (verified, 5 nodes) ====================
__global__ __launch_bounds__(256) void transpose_prep(
    const float* __restrict__ x, u16t* __restrict__ xT,
    const float* __restrict__ th_w, const float* __restrict__ ph_w,
    const float* __restrict__ th_b, const float* __restrict__ ph_b,
    const float* __restrict__ g_w, const float* __restrict__ w_w,
    u16t* __restrict__ Wc, u16t* __restrict__ gwc, u16t* __restrict__ wwc,
    float* __restrict__ bc) {
  __shared__ u16t t[32][33];
  const int b = blockIdx.z, c0 = blockIdx.y * 32, n0 = blockIdx.x * 32;
  const int tid = threadIdx.x;
  {
    const int cl = tid >> 3, n4 = (tid & 7) * 4;
    const float4 v = *(const float4*)(x + ((size_t)b * C_ + c0 + cl) * N_ + n0 + n4);
    t[n4 + 0][cl] = f2h(v.x);
    t[n4 + 1][cl] = f2h(v.y);
    t[n4 + 2][cl] = f2h(v.z);
    t[n4 + 3][cl] = f2h(v.w);
  }
  __syncthreads();
  {
    const int nl = tid >> 3, c4 = (tid & 7) * 4;
    unsigned int lo = (unsigned int)t[nl][c4 + 0] | ((unsigned int)t[nl][c4 + 1] << 16);
    unsigned int hi = (unsigned int)t[nl][c4 + 2] | ((unsigned int)t[nl][c4 + 3] << 16);
    uint2 o; o.x = lo; o.y = hi;
    *(uint2*)(xT + ((size_t)b * N_ + n0 + nl) * C_ + c0 + c4) = o;
  }
  if (blockIdx.y == 0 && blockIdx.z == 0) {
    for (int idx = blockIdx.x * 256 + tid; idx < 131328; idx += 32768) {
      if (idx < 65536) {
        const int j = idx >> 8, c = idx & 255;
        const float v = (j < 128) ? th_w[j * 256 + c] : ph_w[(j - 128) * 256 + c];
        Wc[idx] = f2h(v);
      } else if (idx < 98304) {
        gwc[idx - 65536] = f2h(g_w[idx - 65536]);
      } else if (idx < 131072) {
        wwc[idx - 98304] = f2h(w_w[idx - 98304]);
      } else {
        const int j = idx - 131072;
        bc[j] = (j < 128) ? th_b[j] : ph_b[j - 128];
      }
    }
  }
}

__global__ __launch_bounds__(256)
void gemm_qkv(const u16t* __restrict__ xT, const u16t* __restrict__ Wc,
              const u16t* __restrict__ gwc, const float* __restrict__ bc,
              const float* __restrict__ g_b, u16t* __restrict__ QKo,
              u16t* __restrict__ Vo) {
  __shared__ __attribute__((aligned(16))) u16t lA[128 * 40];
  __shared__ __attribute__((aligned(16))) u16t lB[128 * 40];
  const int z = blockIdx.z, bx = blockIdx.x;
  const u16t* xTb = xT + (size_t)z * N_ * C_;
  const u16t* A; const u16t* B; u16t* Cb; int ldc, m0, j0, colb;
  const float* bias;
  if (bx < 64) {
    A = xTb; B = Wc; Cb = QKo + (size_t)z * N_ * 256; ldc = 256;
    m0 = (bx >> 1) * 128; j0 = (bx & 1) * 128; bias = bc; colb = 1;
  } else {
    A = gwc; B = xTb; Cb = Vo + (size_t)z * D_ * N_; ldc = N_;
    m0 = 0; j0 = (bx - 64) * 128; bias = g_b; colb = 0;
  }
  const int tid = threadIdx.x, lane = tid & 63, wave = tid >> 6;
  const int quad = lane >> 4, l16 = lane & 15;
  const int wm = wave & 1, wj = wave >> 1;

  const f32x4 zero = {0.f, 0.f, 0.f, 0.f};
  f32x4 acc[4][4];
#pragma unroll
  for (int mi = 0; mi < 4; ++mi)
#pragma unroll
    for (int ji = 0; ji < 4; ++ji) acc[mi][ji] = zero;

  for (int k0 = 0; k0 < 256; k0 += 32) {
#pragma unroll
    for (int rr = 0; rr < 2; ++rr) {
      const int idx = rr * 256 + tid;
      const int row = idx >> 2, sg = idx & 3;
      *(uint4*)&lA[row * 40 + sg * 8] = *(const uint4*)(A + (size_t)(m0 + row) * 256 + k0 + sg * 8);
      *(uint4*)&lB[row * 40 + sg * 8] = *(const uint4*)(B + (size_t)(j0 + row) * 256 + k0 + sg * 8);
    }
    __syncthreads();
    f16x8 af[4], bfr[4];
#pragma unroll
    for (int i = 0; i < 4; ++i)
      af[i] = *(const f16x8*)&lA[(wm * 64 + i * 16 + l16) * 40 + quad * 8];
#pragma unroll
    for (int i = 0; i < 4; ++i)
      bfr[i] = *(const f16x8*)&lB[(wj * 64 + i * 16 + l16) * 40 + quad * 8];
#pragma unroll
    for (int mi = 0; mi < 4; ++mi)
#pragma unroll
      for (int ji = 0; ji < 4; ++ji)
        acc[mi][ji] = __builtin_amdgcn_mfma_f32_16x16x32_f16(af[mi], bfr[ji], acc[mi][ji], 0, 0, 0);
    __syncthreads();
  }

  float cb[4];
  if (colb) {
#pragma unroll
    for (int ji = 0; ji < 4; ++ji) cb[ji] = bias[j0 + wj * 64 + ji * 16 + l16];
  }
#pragma unroll
  for (int mi = 0; mi < 4; ++mi) {
#pragma unroll
    for (int r = 0; r < 4; ++r) {
      const int row = m0 + wm * 64 + mi * 16 + quad * 4 + r;
      const float rb = colb ? 0.f : bias[row];
#pragma unroll
      for (int ji = 0; ji < 4; ++ji) {
        const int col = j0 + wj * 64 + ji * 16 + l16;
        const float v = acc[mi][ji][r] + (colb ? cb[ji] : rb);
        Cb[(size_t)row * ldc + col] = f2h(v);
      }
    }
  }
}

__global__ __launch_bounds__(256, 2)
void attn(const u16t* __restrict__ QK, const u16t* __restrict__ V,
          u16t* __restrict__ On0, u16t* __restrict__ On1, float* __restrict__ ml) {
  const int b = blockIdx.y;
  const int split = blockIdx.z;
  const int n0 = blockIdx.x * 128;
  const int kv0 = split * (N_ / 4);
  const int tid = threadIdx.x, lane = tid & 63, wave = tid >> 6;
  const int quad = lane >> 4, l16 = lane & 15;
  const int x7 = l16 & 7;
  __shared__ __attribute__((aligned(16))) u16t Ks[2][64 * 128];
  __shared__ __attribute__((aligned(16))) u16t Vs[2][128 * 64];
  const u16t* QKb = QK + (size_t)b * N_ * 256;
  const u16t* Vb  = V  + (size_t)b * D_ * N_;

  const int krow_l = lane >> 4, kchunk_l = lane & 15;
  const int vrow_l = lane >> 3, vchunk_l = lane & 7;

  f16x8 qf[2][4];
#pragma unroll
  for (int qi = 0; qi < 2; ++qi) {
    const u16t* qrow = QKb + (size_t)(n0 + wave * 32 + qi * 16 + l16) * 256;
#pragma unroll
    for (int kc = 0; kc < 4; ++kc)
      qf[qi][kc] = *(const f16x8*)(qrow + kc * 32 + quad * 8);
  }

  const f32x4 zero = {0.f, 0.f, 0.f, 0.f};
  f32x4 o[2][8];
#pragma unroll
  for (int qi = 0; qi < 2; ++qi)
#pragma unroll
    for (int db = 0; db < 8; ++db) o[qi][db] = zero;
  float m[2] = {-1e30f, -1e30f}, l[2] = {0.f, 0.f};

#pragma unroll
  for (int i = 0; i < 4; ++i) {
    const int krow = (wave * 4 + i) * 4 + krow_l;
    const int kcl = kchunk_l ^ (krow & 7);
    gld_lds16(QKb + (size_t)(kv0 + krow) * 256 + 128 + kcl * 8,
              &Ks[0][(wave * 4 + i) * 512]);
  }
#pragma unroll
  for (int i = 0; i < 4; ++i) {
    const int vrow = (wave * 4 + i) * 8 + vrow_l;
    const int vcl = vchunk_l ^ (vrow & 7);
    gld_lds16(Vb + (size_t)vrow * N_ + kv0 + vcl * 8,
              &Vs[0][(wave * 4 + i) * 512]);
  }
  __syncthreads();

  int cur = 0;
  for (int it = 0; it < 16; ++it) {
    if (it < 15) {
      const int kvn = kv0 + (it + 1) * 64;
#pragma unroll
      for (int i = 0; i < 4; ++i) {
        const int krow = (wave * 4 + i) * 4 + krow_l;
        const int kcl = kchunk_l ^ (krow & 7);
        gld_lds16(QKb + (size_t)(kvn + krow) * 256 + 128 + kcl * 8,
                  &Ks[cur ^ 1][(wave * 4 + i) * 512]);
      }
#pragma unroll
      for (int i = 0; i < 4; ++i) {
        const int vrow = (wave * 4 + i) * 8 + vrow_l;
        const int vcl = vchunk_l ^ (vrow & 7);
        gld_lds16(Vb + (size_t)vrow * N_ + kvn + vcl * 8,
                  &Vs[cur ^ 1][(wave * 4 + i) * 512]);
      }
    }

    const u16t* KsC = &Ks[cur][0];
    const u16t* VsC = &Vs[cur][0];

    f32x4 s[2][4];
#pragma unroll
    for (int qi = 0; qi < 2; ++qi)
#pragma unroll
      for (int ci = 0; ci < 4; ++ci) s[qi][ci] = zero;
#pragma unroll
    for (int kc = 0; kc < 4; ++kc) {
#pragma unroll
      for (int ci = 0; ci < 4; ++ci) {
        f16x8 kf = *(const f16x8*)&KsC[(ci * 16 + l16) * 128 + (((kc * 4 + quad) ^ x7) << 3)];
        s[0][ci] = __builtin_amdgcn_mfma_f32_16x16x32_f16(kf, qf[0][kc], s[0][ci], 0, 0, 0);
        s[1][ci] = __builtin_amdgcn_mfma_f32_16x16x32_f16(kf, qf[1][kc], s[1][ci], 0, 0, 0);
      }
    }

    f16x4 pb[2][4];
#pragma unroll
    for (int qi = 0; qi < 2; ++qi) {
      float m0_ = fmaxf(fmaxf(s[qi][0][0], s[qi][0][1]), fmaxf(s[qi][0][2], s[qi][0][3]));
      float m1_ = fmaxf(fmaxf(s[qi][1][0], s[qi][1][1]), fmaxf(s[qi][1][2], s[qi][1][3]));
      float m2_ = fmaxf(fmaxf(s[qi][2][0], s[qi][2][1]), fmaxf(s[qi][2][2], s[qi][2][3]));
      float m3_ = fmaxf(fmaxf(s[qi][3][0], s[qi][3][1]), fmaxf(s[qi][3][2], s[qi][3][3]));
      float mx = fmaxf(fmaxf(m0_, m1_), fmaxf(m2_, m3_));
      mx = fmaxf(mx, __shfl_xor(mx, 16));
      mx = fmaxf(mx, __shfl_xor(mx, 32));
      const bool defer = __all(mx <= m[qi] + 8.f);
      float mnew = m[qi];
      if (!defer) {
        mnew = fmaxf(m[qi], mx);
        const float alq = __expf(m[qi] - mnew);
        l[qi] *= alq;
#pragma unroll
        for (int db = 0; db < 8; ++db) {
#pragma unroll
          for (int r = 0; r < 4; ++r) o[qi][db][r] *= alq;
        }
        m[qi] = mnew;
      }
      float psum = 0.f;
#pragma unroll
      for (int ci = 0; ci < 4; ++ci) {
#pragma unroll
        for (int r = 0; r < 4; ++r) {
          const float p = __expf(s[qi][ci][r] - mnew);
          psum += p;
          pb[qi][ci][r] = (f16t)p;
        }
      }
      psum += __shfl_xor(psum, 16);
      psum += __shfl_xor(psum, 32);
      l[qi] += psum;
    }

#pragma unroll
    for (int ci = 0; ci < 4; ++ci) {
#pragma unroll
      for (int db = 0; db < 8; ++db) {
        f16x4 av = *(const f16x4*)&VsC[(db * 16 + l16) * 64 +
                                       (((ci * 2 + (quad >> 1)) ^ x7) << 3) + (quad & 1) * 4];
        o[0][db] = __builtin_amdgcn_mfma_f32_16x16x16f16(av, pb[0][ci], o[0][db], 0, 0, 0);
        o[1][db] = __builtin_amdgcn_mfma_f32_16x16x16f16(av, pb[1][ci], o[1][db], 0, 0, 0);
      }
    }
    __syncthreads();
    cur ^= 1;
  }

  u16t* Onb = (split < 2) ? On0 : On1;
  const int sp = split & 1;
#pragma unroll
  for (int qi = 0; qi < 2; ++qi) {
    const int q = n0 + wave * 32 + qi * 16 + l16;
    const float inv = 1.0f / l[qi];
    u16t* yrow = Onb + (((size_t)sp * B_ + b) * N_ + q) * D_;
#pragma unroll
    for (int db = 0; db < 8; ++db) {
      f16x4 pk;
#pragma unroll
      for (int r = 0; r < 4; ++r) pk[r] = (f16t)(o[qi][db][r] * inv);
      *(f16x4*)(yrow + db * 16 + quad * 4) = pk;
    }
    if (quad == 0) {
      float* mlp = ml + ((size_t)split * BN_ + (size_t)b * N_ + q) * 2;
      mlp[0] = m[qi]; mlp[1] = l[qi];
    }
  }
}

__global__ __launch_bounds__(256)
void gemm_wy(const u16t* __restrict__ wwc, const u16t* __restrict__ O0,
             const u16t* __restrict__ O2, const float* __restrict__ ml,
             u16t* __restrict__ wy, const float* __restrict__ w_b) {
  __shared__ __attribute__((aligned(16))) u16t lA[4][128 * 40];
  __shared__ __attribute__((aligned(16))) u16t lB[4][64 * 40];
  __shared__ float wrow[64][4];
  const int z = blockIdx.z;
  const int m0 = blockIdx.y * 128, j0 = blockIdx.x * 64;
  const int tid = threadIdx.x, lane = tid & 63, wave = tid >> 6;
  const int quad = lane >> 4, l16 = lane & 15;
  const int wm = wave & 1, wj = wave >> 1;
  const size_t halfO = (size_t)BN_ * D_;

  uint4 b0[4], b1[4], b2[4], b3[4];
#pragma unroll
  for (int cs = 0; cs < 4; ++cs) {
    const int cid = cs * 256 + tid;
    const int row = cid >> 4, sg = cid & 15;
    const size_t base = ((size_t)z * N_ + j0 + row) * D_ + sg * 8;
    b0[cs] = *(const uint4*)(O0 + base);
    b1[cs] = *(const uint4*)(O0 + halfO + base);
    b2[cs] = *(const uint4*)(O2 + base);
    b3[cs] = *(const uint4*)(O2 + halfO + base);
  }
  uint4 aw[8];
#pragma unroll
  for (int as = 0; as < 8; ++as) {
    const int cid = as * 256 + tid;
    const int row = cid >> 4, sg = cid & 15;
    aw[as] = *(const uint4*)(wwc + (size_t)(m0 + row) * 128 + sg * 8);
  }
  float mlv[8];
  if (tid < 64) {
    const int q = j0 + tid;
#pragma unroll
    for (int s = 0; s < 4; ++s) {
      mlv[2 * s]     = ml[((size_t)s * BN_ + (size_t)z * N_ + q) * 2];
      mlv[2 * s + 1] = ml[((size_t)s * BN_ + (size_t)z * N_ + q) * 2 + 1];
    }
    float mstar = -1e30f;
#pragma unroll
    for (int s = 0; s < 4; ++s) mstar = fmaxf(mstar, mlv[2 * s]);
    float w[4], wsum = 0.f;
#pragma unroll
    for (int s = 0; s < 4; ++s) { w[s] = __expf(mlv[2 * s] - mstar) * mlv[2 * s + 1]; wsum += w[s]; }
    const float inv = 1.0f / wsum;
#pragma unroll
    for (int s = 0; s < 4; ++s) wrow[tid][s] = w[s] * inv;
  }
#pragma unroll
  for (int as = 0; as < 8; ++as) {
    const int cid = as * 256 + tid;
    const int row = cid >> 4, sg = cid & 15;
    *(uint4*)&lA[sg >> 2][row * 40 + (sg & 3) * 8] = aw[as];
  }
  __syncthreads();
#pragma unroll
  for (int cs = 0; cs < 4; ++cs) {
    const int cid = cs * 256 + tid;
    const int row = cid >> 4, sg = cid & 15;
    const float w0 = wrow[row][0], w1 = wrow[row][1];
    const float w2 = wrow[row][2], w3 = wrow[row][3];
    const unsigned* p0 = &b0[cs].x; const unsigned* p1 = &b1[cs].x;
    const unsigned* p2 = &b2[cs].x; const unsigned* p3 = &b3[cs].x;
    uint4 y; unsigned* py = &y.x;
#pragma unroll
    for (int i = 0; i < 4; ++i) {
      const float lo = w0 * h2f((u16t)(p0[i] & 0xffff)) + w1 * h2f((u16t)(p1[i] & 0xffff)) +
                       w2 * h2f((u16t)(p2[i] & 0xffff)) + w3 * h2f((u16t)(p3[i] & 0xffff));
      const float hi = w0 * h2f((u16t)(p0[i] >> 16)) + w1 * h2f((u16t)(p1[i] >> 16)) +
                       w2 * h2f((u16t)(p2[i] >> 16)) + w3 * h2f((u16t)(p3[i] >> 16));
      py[i] = (unsigned)f2h(lo) | ((unsigned)f2h(hi) << 16);
    }
    *(uint4*)&lB[sg >> 2][row * 40 + (sg & 3) * 8] = y;
  }
  __syncthreads();

  const f32x4 zero = {0.f, 0.f, 0.f, 0.f};
  f32x4 acc[4][2];
#pragma unroll
  for (int mi = 0; mi < 4; ++mi)
#pragma unroll
    for (int ji = 0; ji < 2; ++ji) acc[mi][ji] = zero;
#pragma unroll
  for (int kc = 0; kc < 4; ++kc) {
    f16x8 af[4], bfr[2];
#pragma unroll
    for (int i = 0; i < 4; ++i)
      af[i] = *(const f16x8*)&lA[kc][(wm * 64 + i * 16 + l16) * 40 + quad * 8];
#pragma unroll
    for (int i = 0; i < 2; ++i)
      bfr[i] = *(const f16x8*)&lB[kc][(wj * 32 + i * 16 + l16) * 40 + quad * 8];
#pragma unroll
    for (int mi = 0; mi < 4; ++mi)
#pragma unroll
      for (int ji = 0; ji < 2; ++ji)
        acc[mi][ji] = __builtin_amdgcn_mfma_f32_16x16x32_f16(af[mi], bfr[ji], acc[mi][ji], 0, 0, 0);
  }

#pragma unroll
  for (int mi = 0; mi < 4; ++mi) {
#pragma unroll
    for (int r = 0; r < 4; ++r) {
      const int row = m0 + wm * 64 + mi * 16 + quad * 4 + r;
      const float rb = w_b[row];
#pragma unroll
      for (int ji = 0; ji < 2; ++ji) {
        const int col = j0 + wj * 32 + ji * 16 + l16;
        const float v = acc[mi][ji][r] + rb;
        wy[(size_t)z * C_ * N_ + (size_t)row * N_ + col] = f2h(v);
      }
    }
  }
}

__global__ __launch_bounds__(256) void bn_stats_fin(const u16t* __restrict__ wy,
                                                    const float* __restrict__ x,
                                                    const float* __restrict__ gamma,
                                                    const float* __restrict__ beta,
                                                    float* __restrict__ out) {
  const int c = blockIdx.x;
  const int tid = threadIdx.x, lane = tid & 63, wave = tid >> 6;
  __shared__ float red[8];
  __shared__ float mv[2];
  float s1 = 0.f, s2 = 0.f;
#pragma unroll
  for (int it = 0; it < 8; ++it) {
    const int e = (it * 256 + tid) * 8;
    const int z = e >> 12, n = e & 4095;
    const uint4 v = *(const uint4*)(wy + (size_t)z * C_ * N_ + (size_t)c * N_ + n);
    const unsigned* p = &v.x;
#pragma unroll
    for (int i = 0; i < 4; ++i) {
      const float lo = h2f((u16t)(p[i] & 0xffff));
      const float hi = h2f((u16t)(p[i] >> 16));
      s1 += lo + hi;
      s2 += lo * lo + hi * hi;
    }
  }
  s1 += __shfl_xor(s1, 1);  s2 += __shfl_xor(s2, 1);
  s1 += __shfl_xor(s1, 2);  s2 += __shfl_xor(s2, 2);
  s1 += __shfl_xor(s1, 4);  s2 += __shfl_xor(s2, 4);
  s1 += __shfl_xor(s1, 8);  s2 += __shfl_xor(s2, 8);
  s1 += __shfl_xor(s1, 16); s2 += __shfl_xor(s2, 16);
  s1 += __shfl_xor(s1, 32); s2 += __shfl_xor(s2, 32);
  if (lane == 0) { red[wave] = s1; red[4 + wave] = s2; }
  __syncthreads();
  if (tid == 0) {
    const float inv_n = 1.0f / 16384.0f;
    const float tot1 = red[0] + red[1] + red[2] + red[3];
    const float tot2 = red[4] + red[5] + red[6] + red[7];
    const float mean = tot1 * inv_n;
    const float var = tot2 * inv_n - mean * mean;
    mv[0] = mean;
    mv[1] = rsqrtf(var + 1e-5f);
  }
  __syncthreads();
  const float mean = mv[0], rs = mv[1];
  const float g = gamma[c], bt = beta[c];
#pragma unroll
  for (int it = 0; it < 16; ++it) {
    const int e4 = it * 256 + tid;
    const int z = e4 >> 10, n4 = (e4 & 1023) * 4;
    const size_t off = ((size_t)z * C_ + c) * N_ + n4;
    const uint2 wv = *(const uint2*)(wy + off);
    const float4 xv = *(const float4*)(x + off);
    float4 ov;
    ov.x = (h2f((u16t)(wv.x & 0xffff)) - mean) * rs * g + bt + xv.x;
    ov.y = (h2f((u16t)(wv.x >> 16))    - mean) * rs * g + bt + xv.y;
    ov.z = (h2f((u16t)(wv.y & 0xffff)) - mean) * rs * g + bt + xv.z;
    ov.w = (h2f((u16t)(wv.y >> 16))    - mean) * rs * g + bt + xv.w;
    *(float4*)(out + off) = ov;
  }
}

// ---------------- launch: cooperative mega with checked fallback to the 5-node path -------
extern "C" void kernel_launch(void* const* d_in, const int* in_sizes, int n_in,
                              void* d_out, int out_size, void* d_ws, size_t ws_size,
                              hipStream_t stream) {
  const float* x     = (const float*)d_in[0];
  const float* g_w   = (const float*)d_in[1];
  const float* g_b   = (const float*)d_in[2];
  const float* th_w  = (const float*)d_in[3];
  const float* th_b  = (const float*)d_in[4];
  const float* ph_w  = (const float*)d_in[5];
  const float* ph_b  = (const float*)d_in[6];
  const float* w_w   = (const float*)d_in[7];
  const float* w_b   = (const float*)d_in[8];
  const float* gamma = (const float*)d_in[9];
  const float* beta  = (const float*)d_in[10];
  float* out = (float*)d_out;
  char* ws = (char*)d_ws;

  u16t* xT  = (u16t*)(ws);                  // xT, then O0 (attn splits 0,1)
  u16t* QK  = (u16t*)(ws + 8388608);        // QK, then wy
  u16t* V   = (u16t*)(ws + 16777216);
  u16t* Wc  = (u16t*)(ws + 20971520);
  u16t* gwc = (u16t*)(ws + 21102592);
  u16t* wwc = (u16t*)(ws + 21168128);
  float* bc = (float*)(ws + 21233664);
  float* ml = (float*)(ws + 21236736);
  u16t* O2  = (u16t*)d_out;                 // attn splits 2,3 scratch

  void* args[] = {
    (void*)&x,
    (void*)&th_w, (void*)&ph_w, (void*)&th_b, (void*)&ph_b,
    (void*)&g_w, (void*)&g_b, (void*)&w_w, (void*)&w_b,
    (void*)&gamma, (void*)&beta,
    (void*)&out,
    (void*)&xT, (void*)&QK, (void*)&V,
    (void*)&Wc, (void*)&gwc, (void*)&wwc,
    (void*)&bc, (void*)&ml, (void*)&O2,
  };
  hipError_t rc = hipLaunchCooperativeKernel((const void*)mega, dim3(512), dim3(256),
                                             args, 0, stream);
  if (rc != hipSuccess) {
    // cooperative launch rejected (e.g. occupancy validation) -> verified v13 5-node path
    transpose_prep<<<dim3(128, 8, B_), dim3(256), 0, stream>>>(
        x, xT, th_w, ph_w, th_b, ph_b, g_w, w_w, Wc, gwc, wwc, bc);
    gemm_qkv<<<dim3(96, 1, B_), dim3(256), 0, stream>>>(xT, Wc, gwc, bc, g_b, QK, V);
    attn<<<dim3(32, B_, 4), dim3(256), 0, stream>>>(QK, V, xT, O2, ml);
    gemm_wy<<<dim3(64, 2, B_), dim3(256), 0, stream>>>(wwc, xT, O2, ml, QK, w_b);
    bn_stats_fin<<<dim3(256), dim3(256), 0, stream>>>(QK, x, gamma, beta, out);
  }
}

// Round 16
// 166.657 us; speedup vs baseline: 2.5963x; 2.5963x over previous
//
#include <hip/hip_runtime.h>

#define B_ 4
#define C_ 256
#define D_ 128
#define N_ 4096
#define BN_ 16384   // B_*N_

typedef unsigned short u16t;
typedef _Float16 f16t;
typedef f16t f16x8 __attribute__((ext_vector_type(8)));
typedef f16t f16x4 __attribute__((ext_vector_type(4)));
typedef float f32x4 __attribute__((ext_vector_type(4)));

static __device__ __forceinline__ u16t f2h(float f) {
  f16t h = (f16t)f; u16t u; __builtin_memcpy(&u, &h, 2); return u;
}
static __device__ __forceinline__ float h2f(u16t u) {
  f16t h; __builtin_memcpy(&h, &u, 2); return (float)h;
}

// async 16B global->LDS DMA (zero VGPR staging). LDS dest is wave-uniform base + lane*16.
static __device__ __forceinline__ void gld_lds16(const u16t* g, u16t* l) {
  __builtin_amdgcn_global_load_lds(
      (const __attribute__((address_space(1))) void*)g,
      (__attribute__((address_space(3))) void*)l, 16, 0, 0);
}

// ---------------- transpose + cast (x fp32 [B][C][N] -> xT fp16 [B][N][C]) + fused prep ---
// prep_w folded in: blocks with (by==0,bz==0) additionally grid-stride the 131,328 prep
// items (cast weights to fp16, concat theta/phi, biases). Saves one graph node.
__global__ __launch_bounds__(256) void transpose_prep(
    const float* __restrict__ x, u16t* __restrict__ xT,
    const float* __restrict__ th_w, const float* __restrict__ ph_w,
    const float* __restrict__ th_b, const float* __restrict__ ph_b,
    const float* __restrict__ g_w, const float* __restrict__ w_w,
    u16t* __restrict__ Wc, u16t* __restrict__ gwc, u16t* __restrict__ wwc,
    float* __restrict__ bc) {
  __shared__ u16t t[32][33];
  const int b = blockIdx.z, c0 = blockIdx.y * 32, n0 = blockIdx.x * 32;
  const int tid = threadIdx.x;
  {
    const int cl = tid >> 3, n4 = (tid & 7) * 4;
    const float4 v = *(const float4*)(x + ((size_t)b * C_ + c0 + cl) * N_ + n0 + n4);
    t[n4 + 0][cl] = f2h(v.x);
    t[n4 + 1][cl] = f2h(v.y);
    t[n4 + 2][cl] = f2h(v.z);
    t[n4 + 3][cl] = f2h(v.w);
  }
  __syncthreads();
  {
    const int nl = tid >> 3, c4 = (tid & 7) * 4;
    unsigned int lo = (unsigned int)t[nl][c4 + 0] | ((unsigned int)t[nl][c4 + 1] << 16);
    unsigned int hi = (unsigned int)t[nl][c4 + 2] | ((unsigned int)t[nl][c4 + 3] << 16);
    uint2 o; o.x = lo; o.y = hi;
    *(uint2*)(xT + ((size_t)b * N_ + n0 + nl) * C_ + c0 + c4) = o;
  }
  // fused prep: 128 blocks x 256 threads grid-stride 131,328 items
  if (blockIdx.y == 0 && blockIdx.z == 0) {
    for (int idx = blockIdx.x * 256 + tid; idx < 131328; idx += 32768) {
      if (idx < 65536) {
        const int j = idx >> 8, c = idx & 255;
        const float v = (j < 128) ? th_w[j * 256 + c] : ph_w[(j - 128) * 256 + c];
        Wc[idx] = f2h(v);
      } else if (idx < 98304) {
        const int i = idx - 65536;
        gwc[i] = f2h(g_w[i]);
      } else if (idx < 131072) {
        const int i = idx - 98304;
        wwc[i] = f2h(w_w[i]);
      } else {
        const int j = idx - 131072;
        bc[j] = (j < 128) ? th_b[j] : ph_b[j - 128];
      }
    }
  }
}

// ---------------- merged QK + V projection (128x128 tiles, 384 blocks) --------------------
__global__ __launch_bounds__(256)
void gemm_qkv(const u16t* __restrict__ xT, const u16t* __restrict__ Wc,
              const u16t* __restrict__ gwc, const float* __restrict__ bc,
              const float* __restrict__ g_b, u16t* __restrict__ QKo,
              u16t* __restrict__ Vo) {
  __shared__ __attribute__((aligned(16))) u16t lA[128 * 40];
  __shared__ __attribute__((aligned(16))) u16t lB[128 * 40];
  const int z = blockIdx.z, bx = blockIdx.x;
  const u16t* xTb = xT + (size_t)z * N_ * C_;
  const u16t* A; const u16t* B; u16t* Cb; int ldc, m0, j0, colb;
  const float* bias;
  if (bx < 64) {
    A = xTb; B = Wc; Cb = QKo + (size_t)z * N_ * 256; ldc = 256;
    m0 = (bx >> 1) * 128; j0 = (bx & 1) * 128; bias = bc; colb = 1;
  } else {
    A = gwc; B = xTb; Cb = Vo + (size_t)z * D_ * N_; ldc = N_;
    m0 = 0; j0 = (bx - 64) * 128; bias = g_b; colb = 0;
  }
  const int tid = threadIdx.x, lane = tid & 63, wave = tid >> 6;
  const int quad = lane >> 4, l16 = lane & 15;
  const int wm = wave & 1, wj = wave >> 1;

  const f32x4 zero = {0.f, 0.f, 0.f, 0.f};
  f32x4 acc[4][4];
#pragma unroll
  for (int mi = 0; mi < 4; ++mi)
#pragma unroll
    for (int ji = 0; ji < 4; ++ji) acc[mi][ji] = zero;

  for (int k0 = 0; k0 < 256; k0 += 32) {
#pragma unroll
    for (int rr = 0; rr < 2; ++rr) {
      const int idx = rr * 256 + tid;
      const int row = idx >> 2, sg = idx & 3;
      *(uint4*)&lA[row * 40 + sg * 8] = *(const uint4*)(A + (size_t)(m0 + row) * 256 + k0 + sg * 8);
      *(uint4*)&lB[row * 40 + sg * 8] = *(const uint4*)(B + (size_t)(j0 + row) * 256 + k0 + sg * 8);
    }
    __syncthreads();
    f16x8 af[4], bfr[4];
#pragma unroll
    for (int i = 0; i < 4; ++i)
      af[i] = *(const f16x8*)&lA[(wm * 64 + i * 16 + l16) * 40 + quad * 8];
#pragma unroll
    for (int i = 0; i < 4; ++i)
      bfr[i] = *(const f16x8*)&lB[(wj * 64 + i * 16 + l16) * 40 + quad * 8];
#pragma unroll
    for (int mi = 0; mi < 4; ++mi)
#pragma unroll
      for (int ji = 0; ji < 4; ++ji)
        acc[mi][ji] = __builtin_amdgcn_mfma_f32_16x16x32_f16(af[mi], bfr[ji], acc[mi][ji], 0, 0, 0);
    __syncthreads();
  }

  float cb[4];
  if (colb) {
#pragma unroll
    for (int ji = 0; ji < 4; ++ji) cb[ji] = bias[j0 + wj * 64 + ji * 16 + l16];
  }
#pragma unroll
  for (int mi = 0; mi < 4; ++mi) {
#pragma unroll
    for (int r = 0; r < 4; ++r) {
      const int row = m0 + wm * 64 + mi * 16 + quad * 4 + r;
      const float rb = colb ? 0.f : bias[row];
#pragma unroll
      for (int ji = 0; ji < 4; ++ji) {
        const int col = j0 + wj * 64 + ji * 16 + l16;
        const float v = acc[mi][ji][r] + (colb ? cb[ji] : rb);
        Cb[(size_t)row * ldc + col] = f2h(v);
      }
    }
  }
}

// ---------------- flash attention (v11: defer-max + fmax tree, no setprio) ----------------
__global__ __launch_bounds__(256, 2)
void attn(const u16t* __restrict__ QK, const u16t* __restrict__ V,
          u16t* __restrict__ On0, u16t* __restrict__ On1, float* __restrict__ ml) {
  const int b = blockIdx.y;
  const int split = blockIdx.z;
  const int n0 = blockIdx.x * 128;
  const int kv0 = split * (N_ / 4);
  const int tid = threadIdx.x, lane = tid & 63, wave = tid >> 6;
  const int quad = lane >> 4, l16 = lane & 15;
  const int x7 = l16 & 7;  // read-side swizzle key: row&7 == l16&7 for all fragment reads
  __shared__ __attribute__((aligned(16))) u16t Ks[2][64 * 128];   // linear [row][128ch]
  __shared__ __attribute__((aligned(16))) u16t Vs[2][128 * 64];   // linear [d][64kv]
  const u16t* QKb = QK + (size_t)b * N_ * 256;
  const u16t* Vb  = V  + (size_t)b * D_ * N_;

  const int krow_l = lane >> 4, kchunk_l = lane & 15;   // K: 4 rows/issue, 16 chunks/row
  const int vrow_l = lane >> 3, vchunk_l = lane & 7;    // V: 8 rows/issue, 8 chunks/row

  f16x8 qf[2][4];
#pragma unroll
  for (int qi = 0; qi < 2; ++qi) {
    const u16t* qrow = QKb + (size_t)(n0 + wave * 32 + qi * 16 + l16) * 256;
#pragma unroll
    for (int kc = 0; kc < 4; ++kc)
      qf[qi][kc] = *(const f16x8*)(qrow + kc * 32 + quad * 8);
  }

  const f32x4 zero = {0.f, 0.f, 0.f, 0.f};
  f32x4 o[2][8];
#pragma unroll
  for (int qi = 0; qi < 2; ++qi)
#pragma unroll
    for (int db = 0; db < 8; ++db) o[qi][db] = zero;
  float m[2] = {-1e30f, -1e30f}, l[2] = {0.f, 0.f};

#pragma unroll
  for (int i = 0; i < 4; ++i) {
    const int krow = (wave * 4 + i) * 4 + krow_l;
    const int kcl = kchunk_l ^ (krow & 7);
    gld_lds16(QKb + (size_t)(kv0 + krow) * 256 + 128 + kcl * 8,
              &Ks[0][(wave * 4 + i) * 512]);
  }
#pragma unroll
  for (int i = 0; i < 4; ++i) {
    const int vrow = (wave * 4 + i) * 8 + vrow_l;
    const int vcl = vchunk_l ^ (vrow & 7);
    gld_lds16(Vb + (size_t)vrow * N_ + kv0 + vcl * 8,
              &Vs[0][(wave * 4 + i) * 512]);
  }
  __syncthreads();

  int cur = 0;
  for (int it = 0; it < 16; ++it) {
    if (it < 15) {
      const int kvn = kv0 + (it + 1) * 64;
#pragma unroll
      for (int i = 0; i < 4; ++i) {
        const int krow = (wave * 4 + i) * 4 + krow_l;
        const int kcl = kchunk_l ^ (krow & 7);
        gld_lds16(QKb + (size_t)(kvn + krow) * 256 + 128 + kcl * 8,
                  &Ks[cur ^ 1][(wave * 4 + i) * 512]);
      }
#pragma unroll
      for (int i = 0; i < 4; ++i) {
        const int vrow = (wave * 4 + i) * 8 + vrow_l;
        const int vcl = vchunk_l ^ (vrow & 7);
        gld_lds16(Vb + (size_t)vrow * N_ + kvn + vcl * 8,
                  &Vs[cur ^ 1][(wave * 4 + i) * 512]);
      }
    }

    const u16t* KsC = &Ks[cur][0];
    const u16t* VsC = &Vs[cur][0];

    f32x4 s[2][4];
#pragma unroll
    for (int qi = 0; qi < 2; ++qi)
#pragma unroll
      for (int ci = 0; ci < 4; ++ci) s[qi][ci] = zero;
#pragma unroll
    for (int kc = 0; kc < 4; ++kc) {
#pragma unroll
      for (int ci = 0; ci < 4; ++ci) {
        f16x8 kf = *(const f16x8*)&KsC[(ci * 16 + l16) * 128 + (((kc * 4 + quad) ^ x7) << 3)];
        s[0][ci] = __builtin_amdgcn_mfma_f32_16x16x32_f16(kf, qf[0][kc], s[0][ci], 0, 0, 0);
        s[1][ci] = __builtin_amdgcn_mfma_f32_16x16x32_f16(kf, qf[1][kc], s[1][ci], 0, 0, 0);
      }
    }

    f16x4 pb[2][4];
#pragma unroll
    for (int qi = 0; qi < 2; ++qi) {
      float m0_ = fmaxf(fmaxf(s[qi][0][0], s[qi][0][1]), fmaxf(s[qi][0][2], s[qi][0][3]));
      float m1_ = fmaxf(fmaxf(s[qi][1][0], s[qi][1][1]), fmaxf(s[qi][1][2], s[qi][1][3]));
      float m2_ = fmaxf(fmaxf(s[qi][2][0], s[qi][2][1]), fmaxf(s[qi][2][2], s[qi][2][3]));
      float m3_ = fmaxf(fmaxf(s[qi][3][0], s[qi][3][1]), fmaxf(s[qi][3][2], s[qi][3][3]));
      float mx = fmaxf(fmaxf(m0_, m1_), fmaxf(m2_, m3_));
      mx = fmaxf(mx, __shfl_xor(mx, 16));
      mx = fmaxf(mx, __shfl_xor(mx, 32));
      const bool defer = __all(mx <= m[qi] + 8.f);   // wave-uniform
      float mnew = m[qi];
      if (!defer) {
        mnew = fmaxf(m[qi], mx);
        const float alq = __expf(m[qi] - mnew);
        l[qi] *= alq;
#pragma unroll
        for (int db = 0; db < 8; ++db) {
#pragma unroll
          for (int r = 0; r < 4; ++r) o[qi][db][r] *= alq;
        }
        m[qi] = mnew;
      }
      float psum = 0.f;
#pragma unroll
      for (int ci = 0; ci < 4; ++ci) {
#pragma unroll
        for (int r = 0; r < 4; ++r) {
          const float p = __expf(s[qi][ci][r] - mnew);
          psum += p;
          pb[qi][ci][r] = (f16t)p;
        }
      }
      psum += __shfl_xor(psum, 16);
      psum += __shfl_xor(psum, 32);
      l[qi] += psum;
    }

#pragma unroll
    for (int ci = 0; ci < 4; ++ci) {
#pragma unroll
      for (int db = 0; db < 8; ++db) {
        f16x4 av = *(const f16x4*)&VsC[(db * 16 + l16) * 64 +
                                       (((ci * 2 + (quad >> 1)) ^ x7) << 3) + (quad & 1) * 4];
        o[0][db] = __builtin_amdgcn_mfma_f32_16x16x16f16(av, pb[0][ci], o[0][db], 0, 0, 0);
        o[1][db] = __builtin_amdgcn_mfma_f32_16x16x16f16(av, pb[1][ci], o[1][db], 0, 0, 0);
      }
    }
    __syncthreads();
    cur ^= 1;
  }

  u16t* Onb = (split < 2) ? On0 : On1;
  const int sp = split & 1;
#pragma unroll
  for (int qi = 0; qi < 2; ++qi) {
    const int q = n0 + wave * 32 + qi * 16 + l16;
    const float inv = 1.0f / l[qi];
    u16t* yrow = Onb + (((size_t)sp * B_ + b) * N_ + q) * D_;
#pragma unroll
    for (int db = 0; db < 8; ++db) {
      f16x4 pk;
#pragma unroll
      for (int r = 0; r < 4; ++r) pk[r] = (f16t)(o[qi][db][r] * inv);
      *(f16x4*)(yrow + db * 16 + quad * 4) = pk;
    }
    if (quad == 0) {
      float* mlp = ml + ((size_t)split * BN_ + (size_t)b * N_ + q) * 2;
      mlp[0] = m[qi]; mlp[1] = l[qi];
    }
  }
}

// ---------------- w_y GEMM: one-shot staging, no atomics (v11, unchanged) -----------------
__global__ __launch_bounds__(256)
void gemm_wy(const u16t* __restrict__ wwc, const u16t* __restrict__ O0,
             const u16t* __restrict__ O2, const float* __restrict__ ml,
             u16t* __restrict__ wy, const float* __restrict__ w_b) {
  __shared__ __attribute__((aligned(16))) u16t lA[4][128 * 40];
  __shared__ __attribute__((aligned(16))) u16t lB[4][64 * 40];
  __shared__ float wrow[64][4];
  const int z = blockIdx.z;
  const int m0 = blockIdx.y * 128, j0 = blockIdx.x * 64;
  const int tid = threadIdx.x, lane = tid & 63, wave = tid >> 6;
  const int quad = lane >> 4, l16 = lane & 15;
  const int wm = wave & 1, wj = wave >> 1;
  const size_t halfO = (size_t)BN_ * D_;

  uint4 b0[4], b1[4], b2[4], b3[4];
#pragma unroll
  for (int cs = 0; cs < 4; ++cs) {
    const int cid = cs * 256 + tid;
    const int row = cid >> 4, sg = cid & 15;
    const size_t base = ((size_t)z * N_ + j0 + row) * D_ + sg * 8;
    b0[cs] = *(const uint4*)(O0 + base);
    b1[cs] = *(const uint4*)(O0 + halfO + base);
    b2[cs] = *(const uint4*)(O2 + base);
    b3[cs] = *(const uint4*)(O2 + halfO + base);
  }
  uint4 aw[8];
#pragma unroll
  for (int as = 0; as < 8; ++as) {
    const int cid = as * 256 + tid;
    const int row = cid >> 4, sg = cid & 15;
    aw[as] = *(const uint4*)(wwc + (size_t)(m0 + row) * 128 + sg * 8);
  }
  float mlv[8];
  if (tid < 64) {
    const int q = j0 + tid;
#pragma unroll
    for (int s = 0; s < 4; ++s) {
      mlv[2 * s]     = ml[((size_t)s * BN_ + (size_t)z * N_ + q) * 2];
      mlv[2 * s + 1] = ml[((size_t)s * BN_ + (size_t)z * N_ + q) * 2 + 1];
    }
  }
  if (tid < 64) {
    float mstar = -1e30f;
#pragma unroll
    for (int s = 0; s < 4; ++s) mstar = fmaxf(mstar, mlv[2 * s]);
    float w[4], wsum = 0.f;
#pragma unroll
    for (int s = 0; s < 4; ++s) { w[s] = __expf(mlv[2 * s] - mstar) * mlv[2 * s + 1]; wsum += w[s]; }
    const float inv = 1.0f / wsum;
#pragma unroll
    for (int s = 0; s < 4; ++s) wrow[tid][s] = w[s] * inv;
  }
#pragma unroll
  for (int as = 0; as < 8; ++as) {
    const int cid = as * 256 + tid;
    const int row = cid >> 4, sg = cid & 15;
    *(uint4*)&lA[sg >> 2][row * 40 + (sg & 3) * 8] = aw[as];
  }
  __syncthreads();
#pragma unroll
  for (int cs = 0; cs < 4; ++cs) {
    const int cid = cs * 256 + tid;
    const int row = cid >> 4, sg = cid & 15;
    const float w0 = wrow[row][0], w1 = wrow[row][1];
    const float w2 = wrow[row][2], w3 = wrow[row][3];
    const unsigned* p0 = &b0[cs].x; const unsigned* p1 = &b1[cs].x;
    const unsigned* p2 = &b2[cs].x; const unsigned* p3 = &b3[cs].x;
    uint4 y; unsigned* py = &y.x;
#pragma unroll
    for (int i = 0; i < 4; ++i) {
      const float lo = w0 * h2f((u16t)(p0[i] & 0xffff)) + w1 * h2f((u16t)(p1[i] & 0xffff)) +
                       w2 * h2f((u16t)(p2[i] & 0xffff)) + w3 * h2f((u16t)(p3[i] & 0xffff));
      const float hi = w0 * h2f((u16t)(p0[i] >> 16)) + w1 * h2f((u16t)(p1[i] >> 16)) +
                       w2 * h2f((u16t)(p2[i] >> 16)) + w3 * h2f((u16t)(p3[i] >> 16));
      py[i] = (unsigned)f2h(lo) | ((unsigned)f2h(hi) << 16);
    }
    *(uint4*)&lB[sg >> 2][row * 40 + (sg & 3) * 8] = y;
  }
  __syncthreads();

  const f32x4 zero = {0.f, 0.f, 0.f, 0.f};
  f32x4 acc[4][2];
#pragma unroll
  for (int mi = 0; mi < 4; ++mi)
#pragma unroll
    for (int ji = 0; ji < 2; ++ji) acc[mi][ji] = zero;
#pragma unroll
  for (int kc = 0; kc < 4; ++kc) {
    f16x8 af[4], bfr[2];
#pragma unroll
    for (int i = 0; i < 4; ++i)
      af[i] = *(const f16x8*)&lA[kc][(wm * 64 + i * 16 + l16) * 40 + quad * 8];
#pragma unroll
    for (int i = 0; i < 2; ++i)
      bfr[i] = *(const f16x8*)&lB[kc][(wj * 32 + i * 16 + l16) * 40 + quad * 8];
#pragma unroll
    for (int mi = 0; mi < 4; ++mi)
#pragma unroll
      for (int ji = 0; ji < 2; ++ji)
        acc[mi][ji] = __builtin_amdgcn_mfma_f32_16x16x32_f16(af[mi], bfr[ji], acc[mi][ji], 0, 0, 0);
  }

#pragma unroll
  for (int mi = 0; mi < 4; ++mi) {
#pragma unroll
    for (int r = 0; r < 4; ++r) {
      const int row = m0 + wm * 64 + mi * 16 + quad * 4 + r;
      const float rb = w_b[row];
#pragma unroll
      for (int ji = 0; ji < 2; ++ji) {
        const int col = j0 + wj * 32 + ji * 16 + l16;
        const float v = acc[mi][ji][r] + rb;
        wy[(size_t)z * C_ * N_ + (size_t)row * N_ + col] = f2h(v);
      }
    }
  }
}

// ---------------- fused BN stats + finalize: per-channel, NO grid sync --------------------
__global__ __launch_bounds__(256) void bn_stats_fin(const u16t* __restrict__ wy,
                                                    const float* __restrict__ x,
                                                    const float* __restrict__ gamma,
                                                    const float* __restrict__ beta,
                                                    float* __restrict__ out) {
  const int c = blockIdx.x;
  const int tid = threadIdx.x, lane = tid & 63, wave = tid >> 6;
  __shared__ float red[8];
  __shared__ float mv[2];
  float s1 = 0.f, s2 = 0.f;
#pragma unroll
  for (int it = 0; it < 8; ++it) {
    const int e = (it * 256 + tid) * 8;       // element index in [0, 16384)
    const int z = e >> 12, n = e & 4095;
    const uint4 v = *(const uint4*)(wy + (size_t)z * C_ * N_ + (size_t)c * N_ + n);
    const unsigned* p = &v.x;
#pragma unroll
    for (int i = 0; i < 4; ++i) {
      const float lo = h2f((u16t)(p[i] & 0xffff));
      const float hi = h2f((u16t)(p[i] >> 16));
      s1 += lo + hi;
      s2 += lo * lo + hi * hi;
    }
  }
  s1 += __shfl_xor(s1, 1);  s2 += __shfl_xor(s2, 1);
  s1 += __shfl_xor(s1, 2);  s2 += __shfl_xor(s2, 2);
  s1 += __shfl_xor(s1, 4);  s2 += __shfl_xor(s2, 4);
  s1 += __shfl_xor(s1, 8);  s2 += __shfl_xor(s2, 8);
  s1 += __shfl_xor(s1, 16); s2 += __shfl_xor(s2, 16);
  s1 += __shfl_xor(s1, 32); s2 += __shfl_xor(s2, 32);
  if (lane == 0) { red[wave] = s1; red[4 + wave] = s2; }
  __syncthreads();
  if (tid == 0) {
    const float inv_n = 1.0f / 16384.0f;
    const float tot1 = red[0] + red[1] + red[2] + red[3];
    const float tot2 = red[4] + red[5] + red[6] + red[7];
    const float mean = tot1 * inv_n;
    const float var = tot2 * inv_n - mean * mean;
    mv[0] = mean;
    mv[1] = rsqrtf(var + 1e-5f);
  }
  __syncthreads();
  const float mean = mv[0], rs = mv[1];
  const float g = gamma[c], bt = beta[c];
#pragma unroll
  for (int it = 0; it < 16; ++it) {
    const int e4 = it * 256 + tid;            // float4 index within channel, [0, 4096)
    const int z = e4 >> 10, n4 = (e4 & 1023) * 4;
    const size_t off = ((size_t)z * C_ + c) * N_ + n4;
    const uint2 wv = *(const uint2*)(wy + off);
    const float4 xv = *(const float4*)(x + off);
    float4 ov;
    ov.x = (h2f((u16t)(wv.x & 0xffff)) - mean) * rs * g + bt + xv.x;
    ov.y = (h2f((u16t)(wv.x >> 16))    - mean) * rs * g + bt + xv.y;
    ov.z = (h2f((u16t)(wv.y & 0xffff)) - mean) * rs * g + bt + xv.z;
    ov.w = (h2f((u16t)(wv.y >> 16))    - mean) * rs * g + bt + xv.w;
    *(float4*)(out + off) = ov;
  }
}

// ---------------- launch (5 nodes) ----------------
extern "C" void kernel_launch(void* const* d_in, const int* in_sizes, int n_in,
                              void* d_out, int out_size, void* d_ws, size_t ws_size,
                              hipStream_t stream) {
  const float* x     = (const float*)d_in[0];
  const float* g_w   = (const float*)d_in[1];
  const float* g_b   = (const float*)d_in[2];
  const float* th_w  = (const float*)d_in[3];
  const float* th_b  = (const float*)d_in[4];
  const float* ph_w  = (const float*)d_in[5];
  const float* ph_b  = (const float*)d_in[6];
  const float* w_w   = (const float*)d_in[7];
  const float* w_b   = (const float*)d_in[8];
  const float* gamma = (const float*)d_in[9];
  const float* beta  = (const float*)d_in[10];
  float* out = (float*)d_out;
  char* ws = (char*)d_ws;

  u16t* O0  = (u16t*)(ws);                  // attn splits 0,1 (also xT before attn)
  u16t* QK  = (u16t*)(ws + 8388608);
  u16t* wy  = (u16t*)(ws + 8388608);        // overlays QK (QK dead after attn)
  u16t* V   = (u16t*)(ws + 16777216);
  u16t* Wc  = (u16t*)(ws + 20971520);
  u16t* gwc = (u16t*)(ws + 21102592);
  u16t* wwc = (u16t*)(ws + 21168128);
  float* bc = (float*)(ws + 21233664);
  float* ml = (float*)(ws + 21236736);
  u16t* O2 = (u16t*)d_out;                  // attn splits 2,3 scratch (overwritten by bn)

  transpose_prep<<<dim3(128, 8, B_), dim3(256), 0, stream>>>(
      x, (u16t*)ws, th_w, ph_w, th_b, ph_b, g_w, w_w, Wc, gwc, wwc, bc);

  gemm_qkv<<<dim3(96, 1, B_), dim3(256), 0, stream>>>(
      (u16t*)ws, Wc, gwc, bc, g_b, QK, V);

  attn<<<dim3(32, B_, 4), dim3(256), 0, stream>>>(QK, V, O0, O2, ml);

  gemm_wy<<<dim3(64, 2, B_), dim3(256), 0, stream>>>(wwc, O0, O2, ml, wy, w_b);

  bn_stats_fin<<<dim3(256), dim3(256), 0, stream>>>(wy, x, gamma, beta, out);
}